// Round 8
// baseline (4093.031 us; speedup 1.0000x reference)
//
#include <hip/hip_runtime.h>

typedef unsigned short u16;
typedef unsigned char u8;
typedef __attribute__((ext_vector_type(8))) short s16x8;
typedef __attribute__((ext_vector_type(4))) short s16x4;
typedef __attribute__((ext_vector_type(4))) float f32x4;
typedef __attribute__((ext_vector_type(16))) float f32x16;
typedef __attribute__((ext_vector_type(4))) int i32x4;

#define MFMA16(a, b, c) __builtin_amdgcn_mfma_f32_16x16x32_bf16(a, b, c, 0, 0, 0)
#define MFMA32F8(a, b, c) __builtin_amdgcn_mfma_f32_32x32x16_fp8_fp8(a, b, c, 0, 0, 0)
#define EXP2(x) __builtin_amdgcn_exp2f(x)

__device__ __forceinline__ u16 f2bf(float f) {
  unsigned u = __float_as_uint(f);
  u += 0x7FFFu + ((u >> 16) & 1u);
  return (u16)(u >> 16);
}

__device__ __forceinline__ u8 f2fp8(float f) {
  int r = __builtin_amdgcn_cvt_pk_fp8_f32(f, f, 0, false);
  return (u8)(r & 0xff);
}

// async 16B global->LDS. LDS dest is wave-uniform base + lane*16.
__device__ __forceinline__ void async_cp16(const void* g, void* l) {
  __builtin_amdgcn_global_load_lds(
      (__attribute__((address_space(1))) void*)g,
      (__attribute__((address_space(3))) void*)l,
      16, 0, 0);
}

// ---------------- conversion kernels ----------------
__global__ void cvt4(const float* __restrict__ s, u16* __restrict__ d, int n4) {
  int i = blockIdx.x * 256 + threadIdx.x;
  if (i >= n4) return;
  f32x4 v = *(const f32x4*)(s + 4L * i);
  s16x4 o;
  o[0] = (short)f2bf(v[0]); o[1] = (short)f2bf(v[1]);
  o[2] = (short)f2bf(v[2]); o[3] = (short)f2bf(v[3]);
  *(s16x4*)(d + 4L * i) = o;
}

// final_weight [256][256] fp32 -> transposed bf16
__global__ void cvt_t(const float* __restrict__ s, u16* __restrict__ d) {
  int j = blockIdx.x, k = threadIdx.x;
  d[j * 256 + k] = f2bf(s[k * 256 + j]);
}

// ---------------- fused QKV projection GEMM ----------------
// grid (64, gc, 3). Per-block qkv slot = 3MB: Q fp8 1MB | K fp8 1MB | V fp8 1MB.
// z=0: Q=(x@Wq^T+bq)*0.36067 -> fp8 row-major [row][dim].
// z=1: K=(x@Wk^T+bk)*0.25   -> fp8, chunk-packed + XOR-swizzled for identity DMA:
//      chunk cid=2*(dim>>5)|((dim>>3)&1), byte=((dim>>4)&1)*8+(dim&7),
//      addr = key*256 + (cid^(key&7))*16 + byte
//      (0.36067*0.25 = log2e/16: S comes out pre-scaled for exp2 softmax)
// z=2: V^T=Wv@x^T (+bv per dim row) -> fp8, PRE-TILED in attn's V LDS layout:
//      tile jt (32 keys, 8KB): addr = jt*8192 + ((k>>3)&1)*4096 + dim*16
//                                   + ((k>>4)&1)*8 + (k&7)
__global__ __launch_bounds__(256, 4) void gemm_qkv(
    const u16* __restrict__ xb, const u16* __restrict__ wq, const u16* __restrict__ wk,
    const u16* __restrict__ wv, const float* __restrict__ bqv,
    const float* __restrict__ bkv, const float* __restrict__ bvv,
    u8* __restrict__ qkv, int c0) {
  __shared__ __align__(16) u16 lds[16384];
  const int z = blockIdx.z, g = blockIdx.y;
  const u16* A; const u16* B; const float* bias; u8* outb;
  int tiles_n;
  if (z == 0)      { A = xb; B = wq + (long)(c0 + g) * 65536; bias = bqv + (long)(c0 + g) * 256;
                     outb = qkv + (long)g * 3145728;           tiles_n = 2; }
  else if (z == 1) { A = xb; B = wk + (long)(c0 + g) * 65536; bias = bkv + (long)(c0 + g) * 256;
                     outb = qkv + (long)g * 3145728 + 1048576; tiles_n = 2; }
  else             { A = wv + (long)(c0 + g) * 65536; B = xb; bias = bvv + (long)(c0 + g) * 256;
                     outb = qkv + (long)g * 3145728 + 2097152; tiles_n = 32; }

  const int tid = threadIdx.x;
  const int lane = tid & 63;
  const int l15 = lane & 15, q4 = lane >> 4;
  const int w = tid >> 6;
  const int qm = w >> 1, qn = w & 1;
  const int tm = blockIdx.x / tiles_n, tn = blockIdx.x % tiles_n;
  const int row0 = tm << 7, col0 = tn << 7;

  f32x4 C[4][4];
#pragma unroll
  for (int i = 0; i < 4; ++i)
#pragma unroll
    for (int j = 0; j < 4; ++j) C[i][j] = (f32x4)0.0f;

  u16* Al = lds;
  u16* Bl = lds + 8192;

  for (int kc = 0; kc < 4; ++kc) {
    __syncthreads();
#pragma unroll
    for (int i = 0; i < 4; ++i) {
      int s = tid + i * 256;
      int r = s >> 3, p = s & 7;
      async_cp16(A + (long)(row0 + r) * 256 + kc * 64 + ((p ^ (r & 7)) << 3), Al + s * 8);
    }
#pragma unroll
    for (int i = 0; i < 4; ++i) {
      int s = tid + i * 256;
      int r = s >> 3, p = s & 7;
      async_cp16(B + (long)(col0 + r) * 256 + kc * 64 + ((p ^ (r & 7)) << 3), Bl + s * 8);
    }
    __syncthreads();
#pragma unroll
    for (int ks = 0; ks < 2; ++ks) {
      s16x8 a[4];
#pragma unroll
      for (int mt = 0; mt < 4; ++mt) {
        int r = qm * 64 + mt * 16 + l15;
        int kb = ks * 4 + q4;
        a[mt] = *(const s16x8*)(Al + r * 64 + ((kb ^ (r & 7)) << 3));
      }
#pragma unroll
      for (int nt = 0; nt < 4; ++nt) {
        int rn = qn * 64 + nt * 16 + l15;
        int kb = ks * 4 + q4;
        s16x8 b = *(const s16x8*)(Bl + rn * 64 + ((kb ^ (rn & 7)) << 3));
#pragma unroll
        for (int mt = 0; mt < 4; ++mt) C[mt][nt] = MFMA16(a[mt], b, C[mt][nt]);
      }
    }
  }

  const int gr0 = row0 + qm * 64, gc0 = col0 + qn * 64;
  if (z == 0) {
    const float sc = 0.36067376f;
#pragma unroll
    for (int nt = 0; nt < 4; ++nt) {
      int cc = gc0 + nt * 16 + l15;
      float bc = bias[cc];
#pragma unroll
      for (int mt = 0; mt < 4; ++mt)
#pragma unroll
        for (int e = 0; e < 4; ++e) {
          int rr = gr0 + mt * 16 + q4 * 4 + e;
          outb[(long)rr * 256 + cc] = f2fp8((C[mt][nt][e] + bc) * sc);
        }
    }
  } else if (z == 1) {
    const float sc = 0.25f;
#pragma unroll
    for (int nt = 0; nt < 4; ++nt) {
      int cc = gc0 + nt * 16 + l15;  // dim
      float bc = bias[cc];
      int cid = ((cc >> 5) << 1) | ((cc >> 3) & 1);
      int byt = ((cc >> 4) & 1) * 8 + (cc & 7);
#pragma unroll
      for (int mt = 0; mt < 4; ++mt)
#pragma unroll
        for (int e = 0; e < 4; ++e) {
          int key = gr0 + mt * 16 + q4 * 4 + e;
          outb[(long)key * 256 + ((cid ^ (key & 7)) << 4) + byt] =
              f2fp8((C[mt][nt][e] + bc) * sc);
        }
    }
  } else {
    float bm[4][4];
#pragma unroll
    for (int mt = 0; mt < 4; ++mt)
#pragma unroll
      for (int e = 0; e < 4; ++e) bm[mt][e] = bias[gr0 + mt * 16 + q4 * 4 + e];
#pragma unroll
    for (int nt = 0; nt < 4; ++nt) {
      int cc = gc0 + nt * 16 + l15;  // key
      long tb = (long)(cc >> 5) * 8192 + ((cc >> 3) & 1) * 4096 +
                ((cc >> 4) & 1) * 8 + (cc & 7);
#pragma unroll
      for (int mt = 0; mt < 4; ++mt)
#pragma unroll
        for (int e = 0; e < 4; ++e) {
          int rr = gr0 + mt * 16 + q4 * 4 + e;  // dim
          outb[tb + rr * 16] = f2fp8(C[mt][nt][e] + bm[mt][e]);
        }
    }
  }
}

// ---------------- MLP / final GEMM ----------------
// 64x64 tiles, grid 256 (full GPU; was 64 WGs = 1/4 of CUs).
// MODE 2: relu(x@W^T+b) -> bf16 ; MODE 3: sigmoid(x@Wt)+b -> fp32
template <int MODE>
__global__ __launch_bounds__(256, 4) void gemm_bt(
    const u16* __restrict__ A, const u16* __restrict__ B, void* __restrict__ Cout,
    const float* __restrict__ bias) {
  __shared__ __align__(16) u16 lds[8192];
  const int tid = threadIdx.x;
  const int lane = tid & 63;
  const int l15 = lane & 15, q4 = lane >> 4;
  const int w = tid >> 6;
  const int qm = w >> 1, qn = w & 1;
  const int tm = blockIdx.x >> 2, tn = blockIdx.x & 3;
  const int row0 = tm << 6, col0 = tn << 6;

  f32x4 C[2][2];
#pragma unroll
  for (int i = 0; i < 2; ++i)
#pragma unroll
    for (int j = 0; j < 2; ++j) C[i][j] = (f32x4)0.0f;

  u16* Al = lds;
  u16* Bl = lds + 4096;

  for (int kc = 0; kc < 4; ++kc) {
    __syncthreads();
#pragma unroll
    for (int i = 0; i < 2; ++i) {
      int s = tid + i * 256;
      int r = s >> 3, p = s & 7;
      async_cp16(A + (long)(row0 + r) * 256 + kc * 64 + ((p ^ (r & 7)) << 3), Al + s * 8);
    }
#pragma unroll
    for (int i = 0; i < 2; ++i) {
      int s = tid + i * 256;
      int r = s >> 3, p = s & 7;
      async_cp16(B + (long)(col0 + r) * 256 + kc * 64 + ((p ^ (r & 7)) << 3), Bl + s * 8);
    }
    __syncthreads();
#pragma unroll
    for (int ks = 0; ks < 2; ++ks) {
      s16x8 a[2];
#pragma unroll
      for (int mt = 0; mt < 2; ++mt) {
        int r = qm * 32 + mt * 16 + l15;
        int kb = ks * 4 + q4;
        a[mt] = *(const s16x8*)(Al + r * 64 + ((kb ^ (r & 7)) << 3));
      }
#pragma unroll
      for (int nt = 0; nt < 2; ++nt) {
        int rn = qn * 32 + nt * 16 + l15;
        int kb = ks * 4 + q4;
        s16x8 b = *(const s16x8*)(Bl + rn * 64 + ((kb ^ (rn & 7)) << 3));
#pragma unroll
        for (int mt = 0; mt < 2; ++mt) C[mt][nt] = MFMA16(a[mt], b, C[mt][nt]);
      }
    }
  }

  const int gr0 = row0 + qm * 32, gc0 = col0 + qn * 32;
#pragma unroll
  for (int nt = 0; nt < 2; ++nt) {
    int cc = gc0 + nt * 16 + l15;
    float bc = bias[cc];
#pragma unroll
    for (int mt = 0; mt < 2; ++mt)
#pragma unroll
      for (int e = 0; e < 4; ++e) {
        int rr = gr0 + mt * 16 + q4 * 4 + e;
        float v = C[mt][nt][e];
        if (MODE == 2) {
          v = fmaxf(v + bc, 0.0f);
          ((u16*)Cout)[(long)rr * 256 + cc] = f2bf(v);
        } else {
          v = 1.0f / (1.0f + __expf(-v)) + bc;
          ((float*)Cout)[(long)rr * 256 + cc] = v;
        }
      }
  }
}

// ---------------- fused flash attention ----------------
// All-fp8 operands: QK^T fp8 (scales folded: S = qk/16*log2e), PV fp8.
// 2 WGs/CU, G=16 -> 512 WGs (LDS padded to 56KB pins 2/CU; r4: 3/CU thrashes L2).
// r8 restructure: softmax moved INTO the post-barrier compute block, between
// QK(jt+1) and PV(jt). softmax(jt) reads the PREVIOUS S (register-resident) and
// is independent of QK(jt+1) -> same basic block lets the scheduler interleave
// MFMA with softmax VALU (r7 counters: MFMA 2067 + VALU 2130 cyc/SIMD/iter were
// ~perfectly SERIALIZED at 4900 wall; overlap targets wall -> ~max of the two).
// Hot loop is branch-free (guards peeled into 2 tail steps; branches would split
// the scheduling region). K ring 2x8KB (DMA 2 ahead), V ring 2x8KB (DMA 1 ahead),
// ONE barrier/iter. Numerics identical to r5/r7.
__global__ __launch_bounds__(256, 2) void attn(const u8* __restrict__ qkv,
                                               float* __restrict__ acc, int gc, int swiz) {
  __shared__ __align__(16) u8 ldsb[57344];  // K0|K1|V0|V1 (32KB used; padded)

  const int f = blockIdx.x;
  int b, tile;
  if (swiz) { b = (f & 7) + ((f >> 8) << 3); tile = (f >> 3) & 31; }
  else { b = f >> 5; tile = f & 31; }
  if (b >= gc) return;

  const int tid = threadIdx.x;
  const int lane = tid & 63, w = tid >> 6;
  const int l31 = lane & 31, h = lane >> 5;
  const long slot = 3145728L * b;
  const u8* Qg = qkv + slot;
  const u8* Kg = qkv + slot + 1048576;
  const u8* Vg = qkv + slot + 2097152;
  const int rw = tile * 128 + w * 32;

  const int kb256 = l31 * 256;            // K read row base (bytes)
  const int xk = l31 & 7;                 // K read XOR
  const int voffb = h * 4096 + l31 * 16;  // V read base (bytes)

  // Q fragments: 16 k-steps x 8 fp8 dims (1 VGPR pair each)
  long qf[16];
  {
    const u8* qr = Qg + (long)(rw + l31) * 256 + h * 8;
#pragma unroll
    for (int ks = 0; ks < 16; ++ks) qf[ks] = *(const long*)(qr + ks * 16);
  }

  f32x16 O[8];
#pragma unroll
  for (int nt = 0; nt < 8; ++nt) O[nt] = (f32x16)0.0f;
  float rs = 0.0f;

  // prologue: K[0],V[0],K[1] in flight, then QK(0)
#pragma unroll
  for (int i = 0; i < 2; ++i)
    async_cp16(Kg + (tid + i * 256) * 16, ldsb + (tid + i * 256) * 16);
#pragma unroll
  for (int i = 0; i < 2; ++i)
    async_cp16(Vg + (tid + i * 256) * 16, ldsb + 16384 + (tid + i * 256) * 16);
#pragma unroll
  for (int i = 0; i < 2; ++i)
    async_cp16(Kg + 8192 + (tid + i * 256) * 16, ldsb + 8192 + (tid + i * 256) * 16);
  __syncthreads();

  f32x16 Sa = (f32x16)0.0f, Sb = (f32x16)0.0f;
#pragma unroll
  for (int r = 0; r < 8; ++r) {
    i32x4 kv = *(const i32x4*)(ldsb + kb256 + ((((r << 1) | h) ^ xk) << 4));
    union { i32x4 v4; long l2[2]; } ku; ku.v4 = kv;
    Sa = MFMA32F8(ku.l2[0], qf[2 * r], Sa);
    Sb = MFMA32F8(ku.l2[1], qf[2 * r + 1], Sb);
  }

  // One pipeline step for tile J, compile-time parity PC (= J&1).
  // Order: barrier | DMA issue | [ QK(J+1) MFMA || softmax(J) VALU ] | PV(J).
#define ATTN_STEP(J, PC, DOK, DOV, DOQK)                                        \
  {                                                                             \
    __syncthreads(); /* drains DMA {K[J+1], V[J]} issued last step */           \
    if (DOK) {       /* K two ahead -> slot (J+2)&1 == PC */                    \
      const u8* src = Kg + (long)((J) + 2) * 8192;                              \
      u8* dst = ldsb + ((PC) << 13);                                            \
      _Pragma("unroll")                                                         \
      for (int i = 0; i < 2; ++i)                                               \
        async_cp16(src + (tid + i * 256) * 16, dst + (tid + i * 256) * 16);     \
    }                                                                           \
    if (DOV) {       /* V one ahead -> slot (J+1)&1 == PC^1 */                  \
      const u8* src = Vg + (long)((J) + 1) * 8192;                              \
      u8* dst = ldsb + 16384 + (((PC) ^ 1) << 13);                              \
      _Pragma("unroll")                                                         \
      for (int i = 0; i < 2; ++i)                                               \
        async_cp16(src + (tid + i * 256) * 16, dst + (tid + i * 256) * 16);     \
    }                                                                           \
    __builtin_amdgcn_s_setprio(1);                                              \
    f32x16 Sna = (f32x16)0.0f, Snb = (f32x16)0.0f;                              \
    if (DOQK) {      /* QK(J+1) from K slot PC^1, two 8-deep chains */          \
      const u8* Kc = ldsb + (((PC) ^ 1) << 13);                                 \
      _Pragma("unroll")                                                         \
      for (int r = 0; r < 8; ++r) {                                             \
        i32x4 kv = *(const i32x4*)(Kc + kb256 + ((((r << 1) | h) ^ xk) << 4));  \
        union { i32x4 v4; long l2[2]; } ku; ku.v4 = kv;                         \
        Sna = MFMA32F8(ku.l2[0], qf[2 * r], Sna);                               \
        Snb = MFMA32F8(ku.l2[1], qf[2 * r + 1], Snb);                           \
      }                                                                         \
    }                                                                           \
    /* softmax(J) on previous S -- independent of QK(J+1), interleaves */       \
    float p[16];                                                                \
    _Pragma("unroll")                                                           \
    for (int r = 0; r < 16; ++r) {                                              \
      float u = EXP2(-(Sa[r] + Sb[r]));                                         \
      float sg = __builtin_amdgcn_rcpf(1.0f + u);                               \
      p[r] = EXP2(sg * 1.44269504f);                                            \
      rs += p[r];                                                               \
    }                                                                           \
    int P0 = __builtin_amdgcn_cvt_pk_fp8_f32(p[0], p[1], 0, false);             \
    P0 = __builtin_amdgcn_cvt_pk_fp8_f32(p[2], p[3], P0, true);                 \
    int P1 = __builtin_amdgcn_cvt_pk_fp8_f32(p[4], p[5], 0, false);             \
    P1 = __builtin_amdgcn_cvt_pk_fp8_f32(p[6], p[7], P1, true);                 \
    int P2 = __builtin_amdgcn_cvt_pk_fp8_f32(p[8], p[9], 0, false);             \
    P2 = __builtin_amdgcn_cvt_pk_fp8_f32(p[10], p[11], P2, true);               \
    int P3 = __builtin_amdgcn_cvt_pk_fp8_f32(p[12], p[13], 0, false);           \
    P3 = __builtin_amdgcn_cvt_pk_fp8_f32(p[14], p[15], P3, true);               \
    auto s01 = __builtin_amdgcn_permlane32_swap(P0, P1, false, false);          \
    auto s23 = __builtin_amdgcn_permlane32_swap(P2, P3, false, false);          \
    union { int i[2]; long l; } a0u, a1u;                                       \
    a0u.i[0] = (int)s01[0]; a0u.i[1] = (int)s01[1];                             \
    a1u.i[0] = (int)s23[0]; a1u.i[1] = (int)s23[1];                             \
    {  /* PV(J) from V slot PC */                                               \
      const u8* Vc = ldsb + 16384 + ((PC) << 13);                               \
      _Pragma("unroll")                                                         \
      for (int nt = 0; nt < 8; ++nt) {                                          \
        i32x4 vv = *(const i32x4*)(Vc + voffb + nt * 512);                      \
        union { i32x4 v4; long l2[2]; } vu; vu.v4 = vv;                         \
        O[nt] = MFMA32F8(a0u.l, vu.l2[0], O[nt]);                               \
        O[nt] = MFMA32F8(a1u.l, vu.l2[1], O[nt]);                               \
      }                                                                         \
    }                                                                           \
    __builtin_amdgcn_s_setprio(0);                                              \
    Sa = Sna; Sb = Snb;                                                         \
  }

  // branch-free main loop: J = 0..125 (all guards true)
  for (int jt = 0; jt < 126; jt += 2) {
    ATTN_STEP(jt, 0, 1, 1, 1);
    ATTN_STEP(jt + 1, 1, 1, 1, 1);
  }
  // peeled tail: J=126 (no K DMA), J=127 (no DMA, no QK)
  ATTN_STEP(126, 0, 0, 1, 1);
  ATTN_STEP(127, 1, 0, 0, 0);
#undef ATTN_STEP

  // combine row-sum halves, normalize, accumulate (x 1/200)
  float tot = rs + __shfl(rs, lane ^ 32, 64);
#pragma unroll
  for (int r = 0; r < 16; ++r) {
    int qr = (r & 3) + 8 * (r >> 2) + 4 * h;
    float ls = __shfl(tot, qr, 64);
    float scn = 0.005f * __builtin_amdgcn_rcpf(ls);
#pragma unroll
    for (int nt = 0; nt < 8; ++nt)
      unsafeAtomicAdd(acc + (long)(rw + qr) * 256 + nt * 32 + l31, O[nt][r] * scn);
  }
}

// ---------------- host ----------------
extern "C" void kernel_launch(void* const* d_in, const int* in_sizes, int n_in,
                              void* d_out, int out_size, void* d_ws, size_t ws_size,
                              hipStream_t stream) {
  const float* x = (const float*)d_in[0];
  const float* Wq = (const float*)d_in[1];
  const float* bq = (const float*)d_in[2];
  const float* Wk = (const float*)d_in[3];
  const float* bk = (const float*)d_in[4];
  const float* Wv = (const float*)d_in[5];
  const float* bv = (const float*)d_in[6];
  const float* Wl = (const float*)d_in[7];
  const float* bl = (const float*)d_in[8];
  const float* fw = (const float*)d_in[9];
  const float* fb = (const float*)d_in[10];
  float* out = (float*)d_out;

  u16* wsb = (u16*)d_ws;
  u16* xb = wsb;                    // 1,048,576
  u16* wqb = wsb + 1048576;         // 13,107,200
  u16* wkb = wqb + 13107200;
  u16* wvb = wkb + 13107200;
  u16* wlb = wvb + 13107200;        // 1,310,720
  u16* fwtb = wlb + 1310720;        // 65,536
  u16* h0 = fwtb + 65536;           // 1,048,576
  u16* h1 = h0 + 1048576;
  u8* qkvb = (u8*)(h1 + 1048576);   // G * 3 MB

  long fixedBytes = (long)((char*)qkvb - (char*)wsb);
  long avail = (long)ws_size - fixedBytes;
  int G = (int)(avail / 3145728L);
  if (G > 16) G = 16;  // 16 blocks x 32 tiles = 512 WGs = exactly 2/CU
  if (G < 1) G = 1;

  hipMemsetAsync(d_out, 0, (size_t)out_size * sizeof(float), stream);

  cvt4<<<dim3(1024), 256, 0, stream>>>(x, xb, 262144);
  cvt4<<<dim3(12800), 256, 0, stream>>>(Wq, wqb, 3276800);
  cvt4<<<dim3(12800), 256, 0, stream>>>(Wk, wkb, 3276800);
  cvt4<<<dim3(12800), 256, 0, stream>>>(Wv, wvb, 3276800);
  cvt4<<<dim3(1280), 256, 0, stream>>>(Wl, wlb, 327680);
  cvt_t<<<dim3(256), 256, 0, stream>>>(fw, fwtb);

  for (int c0 = 0; c0 < 200; c0 += G) {
    int gc = (200 - c0 < G) ? (200 - c0) : G;
    gemm_qkv<<<dim3(64, gc, 3), 256, 0, stream>>>(xb, wqb, wkb, wvb, bq, bk, bv, qkvb, c0);
    int swiz = (gc == 16 || gc == 8) ? 1 : 0;
    attn<<<dim3(32 * gc), 256, 0, stream>>>(qkvb, out, gc, swiz);
  }

  // MLP: h0 = bf16(acc); 20 x relu-GEMM ping-pong; final sigmoid head
  cvt4<<<dim3(1024), 256, 0, stream>>>(out, h0, 262144);
  for (int i = 0; i < 20; ++i) {
    u16* hin = (i & 1) ? h1 : h0;
    u16* hout = (i & 1) ? h0 : h1;
    gemm_bt<2><<<dim3(256), 256, 0, stream>>>(hin, wlb + (long)i * 65536, hout,
                                              bl + (long)i * 256);
  }
  gemm_bt<3><<<dim3(256), 256, 0, stream>>>(h0, fwtb, d_out, fb);
}

// Round 9
// 3606.919 us; speedup vs baseline: 1.1348x; 1.1348x over previous
//
#include <hip/hip_runtime.h>

typedef unsigned short u16;
typedef unsigned char u8;
typedef __attribute__((ext_vector_type(8))) short s16x8;
typedef __attribute__((ext_vector_type(4))) short s16x4;
typedef __attribute__((ext_vector_type(4))) float f32x4;
typedef __attribute__((ext_vector_type(16))) float f32x16;
typedef __attribute__((ext_vector_type(4))) int i32x4;

#define MFMA16(a, b, c) __builtin_amdgcn_mfma_f32_16x16x32_bf16(a, b, c, 0, 0, 0)
#define MFMA32F8(a, b, c) __builtin_amdgcn_mfma_f32_32x32x16_fp8_fp8(a, b, c, 0, 0, 0)
#define EXP2(x) __builtin_amdgcn_exp2f(x)

__device__ __forceinline__ u16 f2bf(float f) {
  unsigned u = __float_as_uint(f);
  u += 0x7FFFu + ((u >> 16) & 1u);
  return (u16)(u >> 16);
}

__device__ __forceinline__ u8 f2fp8(float f) {
  int r = __builtin_amdgcn_cvt_pk_fp8_f32(f, f, 0, false);
  return (u8)(r & 0xff);
}

// async 16B global->LDS. LDS dest is wave-uniform base + lane*16.
__device__ __forceinline__ void async_cp16(const void* g, void* l) {
  __builtin_amdgcn_global_load_lds(
      (__attribute__((address_space(1))) void*)g,
      (__attribute__((address_space(3))) void*)l,
      16, 0, 0);
}

// ---------------- conversion kernels ----------------
__global__ void cvt4(const float* __restrict__ s, u16* __restrict__ d, int n4) {
  int i = blockIdx.x * 256 + threadIdx.x;
  if (i >= n4) return;
  f32x4 v = *(const f32x4*)(s + 4L * i);
  s16x4 o;
  o[0] = (short)f2bf(v[0]); o[1] = (short)f2bf(v[1]);
  o[2] = (short)f2bf(v[2]); o[3] = (short)f2bf(v[3]);
  *(s16x4*)(d + 4L * i) = o;
}

// final_weight [256][256] fp32 -> transposed bf16
__global__ void cvt_t(const float* __restrict__ s, u16* __restrict__ d) {
  int j = blockIdx.x, k = threadIdx.x;
  d[j * 256 + k] = f2bf(s[k * 256 + j]);
}

// ---------------- fused QKV projection GEMM ----------------
// grid (64, gc, 3). Per-block qkv slot = 3MB: Q fp8 1MB | K fp8 1MB | V fp8 1MB.
// z=0: Q=(x@Wq^T+bq)*0.36067 -> fp8 row-major [row][dim].
// z=1: K=(x@Wk^T+bk)*0.25   -> fp8, chunk-packed + XOR-swizzled for identity DMA:
//      chunk cid=2*(dim>>5)|((dim>>3)&1), byte=((dim>>4)&1)*8+(dim&7),
//      addr = key*256 + (cid^(key&7))*16 + byte
//      (0.36067*0.25 = log2e/16: S comes out pre-scaled for exp2 softmax)
// z=2: V^T=Wv@x^T (+bv per dim row) -> fp8, PRE-TILED in attn's V LDS layout:
//      tile jt (32 keys, 8KB): addr = jt*8192 + ((k>>3)&1)*4096 + dim*16
//                                   + ((k>>4)&1)*8 + (k&7)
__global__ __launch_bounds__(256, 4) void gemm_qkv(
    const u16* __restrict__ xb, const u16* __restrict__ wq, const u16* __restrict__ wk,
    const u16* __restrict__ wv, const float* __restrict__ bqv,
    const float* __restrict__ bkv, const float* __restrict__ bvv,
    u8* __restrict__ qkv, int c0) {
  __shared__ __align__(16) u16 lds[16384];
  const int z = blockIdx.z, g = blockIdx.y;
  const u16* A; const u16* B; const float* bias; u8* outb;
  int tiles_n;
  if (z == 0)      { A = xb; B = wq + (long)(c0 + g) * 65536; bias = bqv + (long)(c0 + g) * 256;
                     outb = qkv + (long)g * 3145728;           tiles_n = 2; }
  else if (z == 1) { A = xb; B = wk + (long)(c0 + g) * 65536; bias = bkv + (long)(c0 + g) * 256;
                     outb = qkv + (long)g * 3145728 + 1048576; tiles_n = 2; }
  else             { A = wv + (long)(c0 + g) * 65536; B = xb; bias = bvv + (long)(c0 + g) * 256;
                     outb = qkv + (long)g * 3145728 + 2097152; tiles_n = 32; }

  const int tid = threadIdx.x;
  const int lane = tid & 63;
  const int l15 = lane & 15, q4 = lane >> 4;
  const int w = tid >> 6;
  const int qm = w >> 1, qn = w & 1;
  const int tm = blockIdx.x / tiles_n, tn = blockIdx.x % tiles_n;
  const int row0 = tm << 7, col0 = tn << 7;

  f32x4 C[4][4];
#pragma unroll
  for (int i = 0; i < 4; ++i)
#pragma unroll
    for (int j = 0; j < 4; ++j) C[i][j] = (f32x4)0.0f;

  u16* Al = lds;
  u16* Bl = lds + 8192;

  for (int kc = 0; kc < 4; ++kc) {
    __syncthreads();
#pragma unroll
    for (int i = 0; i < 4; ++i) {
      int s = tid + i * 256;
      int r = s >> 3, p = s & 7;
      async_cp16(A + (long)(row0 + r) * 256 + kc * 64 + ((p ^ (r & 7)) << 3), Al + s * 8);
    }
#pragma unroll
    for (int i = 0; i < 4; ++i) {
      int s = tid + i * 256;
      int r = s >> 3, p = s & 7;
      async_cp16(B + (long)(col0 + r) * 256 + kc * 64 + ((p ^ (r & 7)) << 3), Bl + s * 8);
    }
    __syncthreads();
#pragma unroll
    for (int ks = 0; ks < 2; ++ks) {
      s16x8 a[4];
#pragma unroll
      for (int mt = 0; mt < 4; ++mt) {
        int r = qm * 64 + mt * 16 + l15;
        int kb = ks * 4 + q4;
        a[mt] = *(const s16x8*)(Al + r * 64 + ((kb ^ (r & 7)) << 3));
      }
#pragma unroll
      for (int nt = 0; nt < 4; ++nt) {
        int rn = qn * 64 + nt * 16 + l15;
        int kb = ks * 4 + q4;
        s16x8 b = *(const s16x8*)(Bl + rn * 64 + ((kb ^ (rn & 7)) << 3));
#pragma unroll
        for (int mt = 0; mt < 4; ++mt) C[mt][nt] = MFMA16(a[mt], b, C[mt][nt]);
      }
    }
  }

  const int gr0 = row0 + qm * 64, gc0 = col0 + qn * 64;
  if (z == 0) {
    const float sc = 0.36067376f;
#pragma unroll
    for (int nt = 0; nt < 4; ++nt) {
      int cc = gc0 + nt * 16 + l15;
      float bc = bias[cc];
#pragma unroll
      for (int mt = 0; mt < 4; ++mt)
#pragma unroll
        for (int e = 0; e < 4; ++e) {
          int rr = gr0 + mt * 16 + q4 * 4 + e;
          outb[(long)rr * 256 + cc] = f2fp8((C[mt][nt][e] + bc) * sc);
        }
    }
  } else if (z == 1) {
    const float sc = 0.25f;
#pragma unroll
    for (int nt = 0; nt < 4; ++nt) {
      int cc = gc0 + nt * 16 + l15;  // dim
      float bc = bias[cc];
      int cid = ((cc >> 5) << 1) | ((cc >> 3) & 1);
      int byt = ((cc >> 4) & 1) * 8 + (cc & 7);
#pragma unroll
      for (int mt = 0; mt < 4; ++mt)
#pragma unroll
        for (int e = 0; e < 4; ++e) {
          int key = gr0 + mt * 16 + q4 * 4 + e;
          outb[(long)key * 256 + ((cid ^ (key & 7)) << 4) + byt] =
              f2fp8((C[mt][nt][e] + bc) * sc);
        }
    }
  } else {
    float bm[4][4];
#pragma unroll
    for (int mt = 0; mt < 4; ++mt)
#pragma unroll
      for (int e = 0; e < 4; ++e) bm[mt][e] = bias[gr0 + mt * 16 + q4 * 4 + e];
#pragma unroll
    for (int nt = 0; nt < 4; ++nt) {
      int cc = gc0 + nt * 16 + l15;  // key
      long tb = (long)(cc >> 5) * 8192 + ((cc >> 3) & 1) * 4096 +
                ((cc >> 4) & 1) * 8 + (cc & 7);
#pragma unroll
      for (int mt = 0; mt < 4; ++mt)
#pragma unroll
        for (int e = 0; e < 4; ++e) {
          int rr = gr0 + mt * 16 + q4 * 4 + e;  // dim
          outb[tb + rr * 16] = f2fp8(C[mt][nt][e] + bm[mt][e]);
        }
    }
  }
}

// ---------------- MLP / final GEMM ----------------
// 64x64 tiles, grid 256 (full GPU; was 64 WGs = 1/4 of CUs).
// MODE 2: relu(x@W^T+b) -> bf16 ; MODE 3: sigmoid(x@Wt)+b -> fp32
template <int MODE>
__global__ __launch_bounds__(256, 4) void gemm_bt(
    const u16* __restrict__ A, const u16* __restrict__ B, void* __restrict__ Cout,
    const float* __restrict__ bias) {
  __shared__ __align__(16) u16 lds[8192];
  const int tid = threadIdx.x;
  const int lane = tid & 63;
  const int l15 = lane & 15, q4 = lane >> 4;
  const int w = tid >> 6;
  const int qm = w >> 1, qn = w & 1;
  const int tm = blockIdx.x >> 2, tn = blockIdx.x & 3;
  const int row0 = tm << 6, col0 = tn << 6;

  f32x4 C[2][2];
#pragma unroll
  for (int i = 0; i < 2; ++i)
#pragma unroll
    for (int j = 0; j < 2; ++j) C[i][j] = (f32x4)0.0f;

  u16* Al = lds;
  u16* Bl = lds + 4096;

  for (int kc = 0; kc < 4; ++kc) {
    __syncthreads();
#pragma unroll
    for (int i = 0; i < 2; ++i) {
      int s = tid + i * 256;
      int r = s >> 3, p = s & 7;
      async_cp16(A + (long)(row0 + r) * 256 + kc * 64 + ((p ^ (r & 7)) << 3), Al + s * 8);
    }
#pragma unroll
    for (int i = 0; i < 2; ++i) {
      int s = tid + i * 256;
      int r = s >> 3, p = s & 7;
      async_cp16(B + (long)(col0 + r) * 256 + kc * 64 + ((p ^ (r & 7)) << 3), Bl + s * 8);
    }
    __syncthreads();
#pragma unroll
    for (int ks = 0; ks < 2; ++ks) {
      s16x8 a[2];
#pragma unroll
      for (int mt = 0; mt < 2; ++mt) {
        int r = qm * 32 + mt * 16 + l15;
        int kb = ks * 4 + q4;
        a[mt] = *(const s16x8*)(Al + r * 64 + ((kb ^ (r & 7)) << 3));
      }
#pragma unroll
      for (int nt = 0; nt < 2; ++nt) {
        int rn = qn * 32 + nt * 16 + l15;
        int kb = ks * 4 + q4;
        s16x8 b = *(const s16x8*)(Bl + rn * 64 + ((kb ^ (rn & 7)) << 3));
#pragma unroll
        for (int mt = 0; mt < 2; ++mt) C[mt][nt] = MFMA16(a[mt], b, C[mt][nt]);
      }
    }
  }

  const int gr0 = row0 + qm * 32, gc0 = col0 + qn * 32;
#pragma unroll
  for (int nt = 0; nt < 2; ++nt) {
    int cc = gc0 + nt * 16 + l15;
    float bc = bias[cc];
#pragma unroll
    for (int mt = 0; mt < 2; ++mt)
#pragma unroll
      for (int e = 0; e < 4; ++e) {
        int rr = gr0 + mt * 16 + q4 * 4 + e;
        float v = C[mt][nt][e];
        if (MODE == 2) {
          v = fmaxf(v + bc, 0.0f);
          ((u16*)Cout)[(long)rr * 256 + cc] = f2bf(v);
        } else {
          v = 1.0f / (1.0f + __expf(-v)) + bc;
          ((float*)Cout)[(long)rr * 256 + cc] = v;
        }
      }
  }
}

// ---------------- fused flash attention ----------------
// All-fp8 operands: QK^T fp8 (scales folded: S = qk/16*log2e), PV fp8.
// 2 WGs/CU, G=16 -> 512 WGs (LDS padded to 56KB pins 2/CU; r4: 3/CU thrashes L2).
// r8: softmax inside the post-barrier block (interleaves with QK MFMA).
// r9: per-WG hashed phase-stagger (s_sleep prologue). The 2 co-resident WGs are
// launch-synchronized running identical schedules -> both sit in MFMA phase then
// both in VALU phase (phase-lock is stable under contention; setprio can't break
// the symmetry). A one-time random delay in [0, ~1 iter) anti-aligns them so one
// wave's MFMA overlaps the other's softmax. Order-independent math: no numerics
// change. Stagger << L2 tile dwell -> no r4-style L2 desync.
// K ring 2x8KB (DMA 2 ahead), V ring 2x8KB (DMA 1 ahead), ONE barrier/iter.
__global__ __launch_bounds__(256, 2) void attn(const u8* __restrict__ qkv,
                                               float* __restrict__ acc, int gc, int swiz) {
  __shared__ __align__(16) u8 ldsb[57344];  // K0|K1|V0|V1 (32KB used; padded)

  const int f = blockIdx.x;
  int b, tile;
  if (swiz) { b = (f & 7) + ((f >> 8) << 3); tile = (f >> 3) & 31; }
  else { b = f >> 5; tile = f & 31; }
  if (b >= gc) return;

  const int tid = threadIdx.x;
  const int lane = tid & 63, w = tid >> 6;
  const int l31 = lane & 31, h = lane >> 5;
  const long slot = 3145728L * b;
  const u8* Qg = qkv + slot;
  const u8* Kg = qkv + slot + 1048576;
  const u8* Vg = qkv + slot + 2097152;
  const int rw = tile * 128 + w * 32;

  const int kb256 = l31 * 256;            // K read row base (bytes)
  const int xk = l31 & 7;                 // K read XOR
  const int voffb = h * 4096 + l31 * 16;  // V read base (bytes)

  // Q fragments: 16 k-steps x 8 fp8 dims (1 VGPR pair each)
  long qf[16];
  {
    const u8* qr = Qg + (long)(rw + l31) * 256 + h * 8;
#pragma unroll
    for (int ks = 0; ks < 16; ++ks) qf[ks] = *(const long*)(qr + ks * 16);
  }

  f32x16 O[8];
#pragma unroll
  for (int nt = 0; nt < 8; ++nt) O[nt] = (f32x16)0.0f;
  float rs = 0.0f;

  // prologue: K[0],V[0],K[1] in flight (DMA proceeds during the stagger sleep)
#pragma unroll
  for (int i = 0; i < 2; ++i)
    async_cp16(Kg + (tid + i * 256) * 16, ldsb + (tid + i * 256) * 16);
#pragma unroll
  for (int i = 0; i < 2; ++i)
    async_cp16(Vg + (tid + i * 256) * 16, ldsb + 16384 + (tid + i * 256) * 16);
#pragma unroll
  for (int i = 0; i < 2; ++i)
    async_cp16(Kg + 8192 + (tid + i * 256) * 16, ldsb + 8192 + (tid + i * 256) * 16);

  // phase-stagger: one-time per-WG random delay, 0..63 x ~64 cyc (0..~4k cyc)
  {
    int dly = (int)(((unsigned)f * 2654435761u) >> 26);
    for (int i = 0; i < dly; ++i) __builtin_amdgcn_s_sleep(1);
  }
  __syncthreads();

  f32x16 Sa = (f32x16)0.0f, Sb = (f32x16)0.0f;
#pragma unroll
  for (int r = 0; r < 8; ++r) {
    i32x4 kv = *(const i32x4*)(ldsb + kb256 + ((((r << 1) | h) ^ xk) << 4));
    union { i32x4 v4; long l2[2]; } ku; ku.v4 = kv;
    Sa = MFMA32F8(ku.l2[0], qf[2 * r], Sa);
    Sb = MFMA32F8(ku.l2[1], qf[2 * r + 1], Sb);
  }

  // One pipeline step for tile J, compile-time parity PC (= J&1).
  // Order: barrier | DMA issue | [ QK(J+1) MFMA || softmax(J) VALU ] | PV(J).
#define ATTN_STEP(J, PC, DOK, DOV, DOQK)                                        \
  {                                                                             \
    __syncthreads(); /* drains DMA {K[J+1], V[J]} issued last step */           \
    if (DOK) {       /* K two ahead -> slot (J+2)&1 == PC */                    \
      const u8* src = Kg + (long)((J) + 2) * 8192;                              \
      u8* dst = ldsb + ((PC) << 13);                                            \
      _Pragma("unroll")                                                         \
      for (int i = 0; i < 2; ++i)                                               \
        async_cp16(src + (tid + i * 256) * 16, dst + (tid + i * 256) * 16);     \
    }                                                                           \
    if (DOV) {       /* V one ahead -> slot (J+1)&1 == PC^1 */                  \
      const u8* src = Vg + (long)((J) + 1) * 8192;                              \
      u8* dst = ldsb + 16384 + (((PC) ^ 1) << 13);                              \
      _Pragma("unroll")                                                         \
      for (int i = 0; i < 2; ++i)                                               \
        async_cp16(src + (tid + i * 256) * 16, dst + (tid + i * 256) * 16);     \
    }                                                                           \
    __builtin_amdgcn_s_setprio(1);                                              \
    f32x16 Sna = (f32x16)0.0f, Snb = (f32x16)0.0f;                              \
    if (DOQK) {      /* QK(J+1) from K slot PC^1, two 8-deep chains */          \
      const u8* Kc = ldsb + (((PC) ^ 1) << 13);                                 \
      _Pragma("unroll")                                                         \
      for (int r = 0; r < 8; ++r) {                                             \
        i32x4 kv = *(const i32x4*)(Kc + kb256 + ((((r << 1) | h) ^ xk) << 4));  \
        union { i32x4 v4; long l2[2]; } ku; ku.v4 = kv;                         \
        Sna = MFMA32F8(ku.l2[0], qf[2 * r], Sna);                               \
        Snb = MFMA32F8(ku.l2[1], qf[2 * r + 1], Snb);                           \
      }                                                                         \
    }                                                                           \
    /* softmax(J) on previous S -- independent of QK(J+1), interleaves */       \
    float p[16];                                                                \
    _Pragma("unroll")                                                           \
    for (int r = 0; r < 16; ++r) {                                              \
      float u = EXP2(-(Sa[r] + Sb[r]));                                         \
      float sg = __builtin_amdgcn_rcpf(1.0f + u);                               \
      p[r] = EXP2(sg * 1.44269504f);                                            \
      rs += p[r];                                                               \
    }                                                                           \
    int P0 = __builtin_amdgcn_cvt_pk_fp8_f32(p[0], p[1], 0, false);             \
    P0 = __builtin_amdgcn_cvt_pk_fp8_f32(p[2], p[3], P0, true);                 \
    int P1 = __builtin_amdgcn_cvt_pk_fp8_f32(p[4], p[5], 0, false);             \
    P1 = __builtin_amdgcn_cvt_pk_fp8_f32(p[6], p[7], P1, true);                 \
    int P2 = __builtin_amdgcn_cvt_pk_fp8_f32(p[8], p[9], 0, false);             \
    P2 = __builtin_amdgcn_cvt_pk_fp8_f32(p[10], p[11], P2, true);               \
    int P3 = __builtin_amdgcn_cvt_pk_fp8_f32(p[12], p[13], 0, false);           \
    P3 = __builtin_amdgcn_cvt_pk_fp8_f32(p[14], p[15], P3, true);               \
    auto s01 = __builtin_amdgcn_permlane32_swap(P0, P1, false, false);          \
    auto s23 = __builtin_amdgcn_permlane32_swap(P2, P3, false, false);          \
    union { int i[2]; long l; } a0u, a1u;                                       \
    a0u.i[0] = (int)s01[0]; a0u.i[1] = (int)s01[1];                             \
    a1u.i[0] = (int)s23[0]; a1u.i[1] = (int)s23[1];                             \
    {  /* PV(J) from V slot PC */                                               \
      const u8* Vc = ldsb + 16384 + ((PC) << 13);                               \
      _Pragma("unroll")                                                         \
      for (int nt = 0; nt < 8; ++nt) {                                          \
        i32x4 vv = *(const i32x4*)(Vc + voffb + nt * 512);                      \
        union { i32x4 v4; long l2[2]; } vu; vu.v4 = vv;                         \
        O[nt] = MFMA32F8(a0u.l, vu.l2[0], O[nt]);                               \
        O[nt] = MFMA32F8(a1u.l, vu.l2[1], O[nt]);                               \
      }                                                                         \
    }                                                                           \
    __builtin_amdgcn_s_setprio(0);                                              \
    Sa = Sna; Sb = Snb;                                                         \
  }

  // branch-free main loop: J = 0..125 (all guards true)
  for (int jt = 0; jt < 126; jt += 2) {
    ATTN_STEP(jt, 0, 1, 1, 1);
    ATTN_STEP(jt + 1, 1, 1, 1, 1);
  }
  // peeled tail: J=126 (no K DMA), J=127 (no DMA, no QK)
  ATTN_STEP(126, 0, 0, 1, 1);
  ATTN_STEP(127, 1, 0, 0, 0);
#undef ATTN_STEP

  // combine row-sum halves, normalize, accumulate (x 1/200)
  float tot = rs + __shfl(rs, lane ^ 32, 64);
#pragma unroll
  for (int r = 0; r < 16; ++r) {
    int qr = (r & 3) + 8 * (r >> 2) + 4 * h;
    float ls = __shfl(tot, qr, 64);
    float scn = 0.005f * __builtin_amdgcn_rcpf(ls);
#pragma unroll
    for (int nt = 0; nt < 8; ++nt)
      unsafeAtomicAdd(acc + (long)(rw + qr) * 256 + nt * 32 + l31, O[nt][r] * scn);
  }
}

// ---------------- host ----------------
extern "C" void kernel_launch(void* const* d_in, const int* in_sizes, int n_in,
                              void* d_out, int out_size, void* d_ws, size_t ws_size,
                              hipStream_t stream) {
  const float* x = (const float*)d_in[0];
  const float* Wq = (const float*)d_in[1];
  const float* bq = (const float*)d_in[2];
  const float* Wk = (const float*)d_in[3];
  const float* bk = (const float*)d_in[4];
  const float* Wv = (const float*)d_in[5];
  const float* bv = (const float*)d_in[6];
  const float* Wl = (const float*)d_in[7];
  const float* bl = (const float*)d_in[8];
  const float* fw = (const float*)d_in[9];
  const float* fb = (const float*)d_in[10];
  float* out = (float*)d_out;

  u16* wsb = (u16*)d_ws;
  u16* xb = wsb;                    // 1,048,576
  u16* wqb = wsb + 1048576;         // 13,107,200
  u16* wkb = wqb + 13107200;
  u16* wvb = wkb + 13107200;
  u16* wlb = wvb + 13107200;        // 1,310,720
  u16* fwtb = wlb + 1310720;        // 65,536
  u16* h0 = fwtb + 65536;           // 1,048,576
  u16* h1 = h0 + 1048576;
  u8* qkvb = (u8*)(h1 + 1048576);   // G * 3 MB

  long fixedBytes = (long)((char*)qkvb - (char*)wsb);
  long avail = (long)ws_size - fixedBytes;
  int G = (int)(avail / 3145728L);
  if (G > 16) G = 16;  // 16 blocks x 32 tiles = 512 WGs = exactly 2/CU
  if (G < 1) G = 1;

  hipMemsetAsync(d_out, 0, (size_t)out_size * sizeof(float), stream);

  cvt4<<<dim3(1024), 256, 0, stream>>>(x, xb, 262144);
  cvt4<<<dim3(12800), 256, 0, stream>>>(Wq, wqb, 3276800);
  cvt4<<<dim3(12800), 256, 0, stream>>>(Wk, wkb, 3276800);
  cvt4<<<dim3(12800), 256, 0, stream>>>(Wv, wvb, 3276800);
  cvt4<<<dim3(1280), 256, 0, stream>>>(Wl, wlb, 327680);
  cvt_t<<<dim3(256), 256, 0, stream>>>(fw, fwtb);

  for (int c0 = 0; c0 < 200; c0 += G) {
    int gc = (200 - c0 < G) ? (200 - c0) : G;
    gemm_qkv<<<dim3(64, gc, 3), 256, 0, stream>>>(xb, wqb, wkb, wvb, bq, bk, bv, qkvb, c0);
    int swiz = (gc == 16 || gc == 8) ? 1 : 0;
    attn<<<dim3(32 * gc), 256, 0, stream>>>(qkvb, out, gc, swiz);
  }

  // MLP: h0 = bf16(acc); 20 x relu-GEMM ping-pong; final sigmoid head
  cvt4<<<dim3(1024), 256, 0, stream>>>(out, h0, 262144);
  for (int i = 0; i < 20; ++i) {
    u16* hin = (i & 1) ? h1 : h0;
    u16* hout = (i & 1) ? h0 : h1;
    gemm_bt<2><<<dim3(256), 256, 0, stream>>>(hin, wlb + (long)i * 65536, hout,
                                              bl + (long)i * 256);
  }
  gemm_bt<3><<<dim3(256), 256, 0, stream>>>(h0, fwtb, d_out, fb);
}